// Round 8
// baseline (241.758 us; speedup 1.0000x reference)
//
#include <hip/hip_runtime.h>
#include <cstdint>
#include <cstddef>

#define NH 8
#define DH 64
#define DM 512
#define CTX 64
#define BB 2
#define QL 2048
#define TT (QL + CTX - 1)   // 2111
#define HDIM 512
#define KVN 1024
#define KD 512              // K for all GEMMs

typedef unsigned short u16;
typedef __attribute__((ext_vector_type(8))) short bf16x8;   // 8 bf16 = 4 VGPRs
typedef __attribute__((ext_vector_type(4))) float f32x4;

__device__ __forceinline__ u16 f2bf(float f) {      // RNE float->bf16
    uint32_t u = __float_as_uint(f);
    u += 0x7FFF + ((u >> 16) & 1);
    return (u16)(u >> 16);
}
__device__ __forceinline__ uint32_t packbf(float lo, float hi) { // 2xbf16 in u32
    return (uint32_t)f2bf(lo) | ((uint32_t)f2bf(hi) << 16);
}

#define GLLDS(g, l) __builtin_amdgcn_global_load_lds( \
    (const __attribute__((address_space(1))) void*)(g), \
    (__attribute__((address_space(3))) void*)(l), 16, 0, 0)

// ---------------------------------------------------------------------------
// Launch 1: G1 (bid<792) + G3 (792<=bid<800) + mask/ctr-zero (800<=bid<928).
// A reg-staged from fp32 (x or r); B reg-staged DIRECTLY from fp32 weights
// (k-major W[k][n]): thread (kkp=tid&15, c4n=(tid>>4)*4) loads 2 adjacent-k
// float4, packs k-pairs, writes 4 u32 into Bs[n][k] with 40-u16 row stride
// (16B-aligned rows for b128 reads; 2-way write banks = free).
// 128(M)x64(N) tiles, 2-phase prefetch, one barrier per K-step.
// ---------------------------------------------------------------------------
__global__ __launch_bounds__(256) void gemm_fused(
    const float* __restrict__ x, const float* __restrict__ Wkv,
    const float* __restrict__ Wq, const float* __restrict__ bq,
    const float* __restrict__ r, const float* __restrict__ Wr,
    u16* __restrict__ kvb, u16* __restrict__ hqb, u16* __restrict__ hrb,
    float* __restrict__ maskv, int* __restrict__ ctrs)
{
    const int bid = blockIdx.x;
    const int tid = threadIdx.x;

    if (bid >= 800) {                           // pad-mask + ctr zero
        __shared__ int anyflag;
        int idx = bid - 800;
        if (idx == 0 && tid < 64) ctrs[tid] = 0;
        int t = idx >> 1, b = idx & 1;
        const float* row = x + (size_t)(b * TT + t) * DM;
        bool nz = (row[tid] != 0.f) || (row[tid + 256] != 0.f);
        if (tid == 0) anyflag = 0;
        __syncthreads();
        unsigned long long bal = __ballot(nz);
        if ((tid & 63) == 0 && bal) atomicOr(&anyflag, 1);
        __syncthreads();
        if (tid == 0) maskv[b * 64 + t] = anyflag ? 0.f : -1e30f;
        return;
    }

    __shared__ __align__(16) u16 As[2][128 * 32];   // 16 KB
    __shared__ __align__(16) u16 Bs[2][64 * 40];    // 10 KB (stride 40 u16)

    const int lane = tid & 63;
    const int w    = tid >> 6;
    const int wm   = w * 32;                        // wave owns 32 M-rows

    const bool g3 = (bid >= 792);
    const float* A; const float* Bw; int ldb, coln, m0, n0, mrows;
    if (g3) {
        A = r; m0 = 0; n0 = (bid - 792) * 64; mrows = CTX;
        Bw = Wr; ldb = 512; coln = n0;
    } else {
        A = x; m0 = (bid / 24) * 128; n0 = (bid % 24) * 64; mrows = BB * TT;
        if (n0 < 1024) { Bw = Wkv; ldb = 1024; coln = n0; }
        else           { Bw = Wq;  ldb = 512;  coln = n0 - 1024; }
    }

    // A staging: thread covers row=tid>>1, k-half=(tid&1)*16 (16 fp32)
    const int arow = tid >> 1;
    const int akh  = (tid & 1) * 16;
    int grow = m0 + arow; if (grow >= mrows) grow = 0;   // clamp (outputs guarded)
    const float* gA = A + (size_t)grow * KD + akh;

    // B staging: thread covers k-pair kkp, 4 n at c4n
    const int kkp = tid & 15;
    const int c4n = (tid >> 4) * 4;
    const float* gB0 = Bw + (size_t)(2 * kkp) * ldb + coln + c4n;
    const float* gB1 = gB0 + ldb;

    float4 f0, f1, f2, f3, ba, bb;
#define ALOAD1(kt) do { \
    f0 = *(const float4*)(gA + (kt));      f1 = *(const float4*)(gA + (kt) + 4); \
    f2 = *(const float4*)(gA + (kt) + 8);  f3 = *(const float4*)(gA + (kt) + 12); \
} while (0)
#define AWRITE1(buf) do { \
    uint4 p0, p1; \
    p0.x = packbf(f0.x, f0.y); p0.y = packbf(f0.z, f0.w); \
    p0.z = packbf(f1.x, f1.y); p0.w = packbf(f1.z, f1.w); \
    p1.x = packbf(f2.x, f2.y); p1.y = packbf(f2.z, f2.w); \
    p1.z = packbf(f3.x, f3.y); p1.w = packbf(f3.z, f3.w); \
    *(uint4*)&As[buf][arow * 32 + akh]     = p0; \
    *(uint4*)&As[buf][arow * 32 + akh + 8] = p1; \
} while (0)
#define BLOAD1(kt) do { \
    ba = *(const float4*)(gB0 + (size_t)(kt) * ldb); \
    bb = *(const float4*)(gB1 + (size_t)(kt) * ldb); \
} while (0)
#define BWRITE1(buf) do { \
    uint32_t* d = (uint32_t*)&Bs[buf][0]; \
    d[(c4n + 0) * 20 + kkp] = packbf(ba.x, bb.x); \
    d[(c4n + 1) * 20 + kkp] = packbf(ba.y, bb.y); \
    d[(c4n + 2) * 20 + kkp] = packbf(ba.z, bb.z); \
    d[(c4n + 3) * 20 + kkp] = packbf(ba.w, bb.w); \
} while (0)

    f32x4 acc[2][4];
#pragma unroll
    for (int i = 0; i < 2; i++)
#pragma unroll
        for (int j = 0; j < 4; j++)
            acc[i][j] = (f32x4){0.f, 0.f, 0.f, 0.f};

    ALOAD1(0); BLOAD1(0);
    AWRITE1(0); BWRITE1(0);
    __syncthreads();

    int cur = 0;
    const int fm = lane & 15;
    const int fk = (lane >> 4) * 8;
    for (int kt = 0; kt < KD; kt += 32) {
        const bool more = (kt + 32 < KD);
        if (more) { ALOAD1(kt + 32); BLOAD1(kt + 32); }

        bf16x8 af[2], bfr[4];
#pragma unroll
        for (int i = 0; i < 2; i++)
            af[i] = *(const bf16x8*)&As[cur][(wm + i * 16 + fm) * 32 + fk];
#pragma unroll
        for (int j = 0; j < 4; j++)
            bfr[j] = *(const bf16x8*)&Bs[cur][(j * 16 + fm) * 40 + fk];
#pragma unroll
        for (int i = 0; i < 2; i++)
#pragma unroll
            for (int j = 0; j < 4; j++)
                acc[i][j] = __builtin_amdgcn_mfma_f32_16x16x32_bf16(af[i], bfr[j], acc[i][j], 0, 0, 0);

        if (more) { AWRITE1(cur ^ 1); BWRITE1(cur ^ 1); }
        __syncthreads();
        cur ^= 1;
    }
#undef ALOAD1
#undef AWRITE1
#undef BLOAD1
#undef BWRITE1

    const int fc = lane & 15;
    const int fr = (lane >> 4) * 4;
    if (!g3) {
        const bool iskv = (n0 < 1024);
#pragma unroll
        for (int i = 0; i < 2; i++)
#pragma unroll
            for (int rr = 0; rr < 4; rr++) {
                int row = m0 + wm + i * 16 + fr + rr;
                if (row < BB * TT) {
                    if (iskv) {
#pragma unroll
                        for (int j = 0; j < 4; j++) {
                            int col = n0 + j * 16 + fc;
                            kvb[(size_t)row * KVN + col] = f2bf(acc[i][j][rr]);
                        }
                    } else {
                        int bb2 = row / TT;
                        int t   = row - bb2 * TT;
                        if (t >= CTX - 1) {
                            size_t orow = (size_t)(bb2 * QL + t - (CTX - 1));
#pragma unroll
                            for (int j = 0; j < 4; j++) {
                                int col = n0 + j * 16 + fc - 1024;
                                hqb[orow * HDIM + col] = f2bf(acc[i][j][rr] + bq[col]);
                            }
                        }
                    }
                }
            }
    } else {
#pragma unroll
        for (int i = 0; i < 2; i++)
#pragma unroll
            for (int rr = 0; rr < 4; rr++) {
                int row = m0 + wm + i * 16 + fr + rr;
                if (row < CTX) {
#pragma unroll
                    for (int j = 0; j < 4; j++) {
                        int col = n0 + j * 16 + fc;
                        hrb[(size_t)row * HDIM + col] = f2bf(acc[i][j][rr]);
                    }
                }
            }
    }
}

// ---------------------------------------------------------------------------
// Launch 2: attention + last-arriver O-projection.
// Attn phase identical to R7 (verified). Then: threadfence + atomicAdd on
// ctr[b, qtile]; the 8th arriver (all heads of these 64 q-rows done) computes
// out[64 x 512] = attnb[64 x 512] @ Wo (fp32 Wo staged like G1's B; A GLLDS).
// No spinning -> no deadlock possible. Coherence via device-scope fence+atomic.
// LDS: attn 37888 | G2 reuse: As2 2x4KB @0, Bs2 20KB @8192.
// ---------------------------------------------------------------------------
__global__ __launch_bounds__(256) void attn_mfma(
    const u16* __restrict__ kvb, const u16* __restrict__ hqb,
    const u16* __restrict__ hrb, const float* __restrict__ maskv,
    u16* __restrict__ attnb, const float* __restrict__ Wo,
    float* __restrict__ out, int* __restrict__ ctrs)
{
    __shared__ __align__(16) char lds[37888];
    __shared__ int lastflag;
    float* sprime = (float*)lds;                 // [4][16][80] (band RMW stride 81)
    u16*   vTs    = (u16*)lds;                   // [64][136] — aliases sprime
    u16*   wband  = (u16*)(lds + 20480);         // [64][136]

    const int q0 = blockIdx.x * 64;
    const int h  = blockIdx.y;
    const int b  = blockIdx.z;
    const int tid  = threadIdx.x;
    const int lane = tid & 63;
    const int w    = tid >> 6;
    const int qb   = q0 + w * 16;

    // ---- issue V loads early: 8 ushort4/thread, in flight until vTs write ----
    const int vr0 = tid >> 4;
    const int vc4 = (tid & 15) * 4;
    ushort4 vreg[8];
#pragma unroll
    for (int i = 0; i < 8; i++) {
        int rr = vr0 + i * 16;
        if (rr < 127)
            vreg[i] = *(const ushort4*)&kvb[(size_t)(b * TT + q0 + rr) * KVN + HDIM + h * DH + vc4];
        else
            vreg[i] = (ushort4){0, 0, 0, 0};     // pad column t=127 stays zero
    }

    // zero W' band buffer (64*136 u16 = 4352 u32)
    {
        uint32_t* wz = (uint32_t*)wband;
#pragma unroll
        for (int i = 0; i < 17; i++) wz[tid + i * 256] = 0;
    }
    // raw barrier with lgkm-only drain: V loads (vmcnt) stay outstanding
    asm volatile("s_waitcnt lgkmcnt(0)" ::: "memory");
    __builtin_amdgcn_s_barrier();

    const int fm = lane & 15;
    const int fk = (lane >> 4) * 8;

    const u16* hqrow = hqb + (size_t)(b * QL + qb + fm) * HDIM + h * DH + fk;
    bf16x8 afr0 = *(const bf16x8*)(hqrow);
    bf16x8 afr1 = *(const bf16x8*)(hqrow + 32);

    // ---- QK': S'[16 x 80] ----
    {
        const u16* kbase = kvb + (size_t)(b * TT + qb + fm) * KVN + h * DH + fk;
#pragma unroll
        for (int nt = 0; nt < 5; nt++) {
            bf16x8 b0 = *(const bf16x8*)(kbase + (size_t)nt * 16 * KVN);
            bf16x8 b1 = *(const bf16x8*)(kbase + (size_t)nt * 16 * KVN + 32);
            f32x4 acc = (f32x4){0.f, 0.f, 0.f, 0.f};
            acc = __builtin_amdgcn_mfma_f32_16x16x32_bf16(afr0, b0, acc, 0, 0, 0);
            acc = __builtin_amdgcn_mfma_f32_16x16x32_bf16(afr1, b1, acc, 0, 0, 0);
            const int row = (lane >> 4) * 4;
#pragma unroll
            for (int r2 = 0; r2 < 4; r2++)
                sprime[w * 1280 + (row + r2) * 80 + nt * 16 + fm] = acc[r2];
        }
    }
    // ---- S2 folded into sprime: s[m][m+c] += S2[m][c] (stride-81 band) ----
    {
        const u16* hrbase = hrb + (size_t)fm * HDIM + h * DH + fk;
#pragma unroll
        for (int nc = 0; nc < 4; nc++) {
            bf16x8 b0 = *(const bf16x8*)(hrbase + (size_t)nc * 16 * HDIM);
            bf16x8 b1 = *(const bf16x8*)(hrbase + (size_t)nc * 16 * HDIM + 32);
            f32x4 acc = (f32x4){0.f, 0.f, 0.f, 0.f};
            acc = __builtin_amdgcn_mfma_f32_16x16x32_bf16(afr0, b0, acc, 0, 0, 0);
            acc = __builtin_amdgcn_mfma_f32_16x16x32_bf16(afr1, b1, acc, 0, 0, 0);
            const int row = (lane >> 4) * 4;
#pragma unroll
            for (int r2 = 0; r2 < 4; r2++)
                sprime[w * 1280 + (row + r2) * 81 + nc * 16 + fm] += acc[r2];
        }
    }

    // ---- wave-parallel softmax: 4 lanes per row ----
    {
        const int i  = lane >> 2;
        const int g  = lane & 3;
        const int qloc = w * 16 + i;
        const float* srow = &sprime[w * 1280 + i * 81 + g * 16];
        float sv[16];
#pragma unroll
        for (int j = 0; j < 16; j++) sv[j] = srow[j] * 0.125f;
        if (q0 == 0) {
#pragma unroll
            for (int j = 0; j < 16; j++) {
                int t = qloc + g * 16 + j;
                if (t < 63) sv[j] += maskv[b * 64 + t];
            }
        }
        float mx = sv[0];
#pragma unroll
        for (int j = 1; j < 16; j++) mx = fmaxf(mx, sv[j]);
        mx = fmaxf(mx, __shfl_xor(mx, 1, 64));
        mx = fmaxf(mx, __shfl_xor(mx, 2, 64));
        float sum = 0.f;
#pragma unroll
        for (int j = 0; j < 16; j++) { sv[j] = __expf(sv[j] - mx); sum += sv[j]; }
        sum += __shfl_xor(sum, 1, 64);
        sum += __shfl_xor(sum, 2, 64);
        float inv = 1.f / sum;
        u16* wrow = &wband[qloc * 136 + qloc + g * 16];
#pragma unroll
        for (int j = 0; j < 16; j++) wrow[j] = f2bf(sv[j] * inv);
    }
    __syncthreads();   // ALL waves done reading sprime; wband complete

    // ---- write V transposed into sprime's (now dead) space ----
#pragma unroll
    for (int i = 0; i < 8; i++) {
        int rr = vr0 + i * 16;
        vTs[(vc4 + 0) * 136 + rr] = vreg[i].x;
        vTs[(vc4 + 1) * 136 + rr] = vreg[i].y;
        vTs[(vc4 + 2) * 136 + rr] = vreg[i].z;
        vTs[(vc4 + 3) * 136 + rr] = vreg[i].w;
    }
    __syncthreads();   // vTs complete

    // ---- PV: O[16 x 64] per wave = W'[16 x 128] @ V[128 x 64] ----
    f32x4 oacc[4];
#pragma unroll
    for (int j = 0; j < 4; j++) oacc[j] = (f32x4){0.f, 0.f, 0.f, 0.f};
#pragma unroll
    for (int ks = 0; ks < 4; ks++) {
        bf16x8 wa = *(const bf16x8*)&wband[(w * 16 + fm) * 136 + ks * 32 + fk];
#pragma unroll
        for (int j = 0; j < 4; j++) {
            bf16x8 vb = *(const bf16x8*)&vTs[(j * 16 + fm) * 136 + ks * 32 + fk];
            oacc[j] = __builtin_amdgcn_mfma_f32_16x16x32_bf16(wa, vb, oacc[j], 0, 0, 0);
        }
    }
    {
        const int row = (lane >> 4) * 4;
#pragma unroll
        for (int j = 0; j < 4; j++)
#pragma unroll
            for (int r2 = 0; r2 < 4; r2++)
                attnb[(size_t)(b * QL + qb + row + r2) * HDIM + h * DH + j * 16 + fm] =
                    f2bf(oacc[j][r2]);
    }

    // ---- arrival: release our attnb rows; 8th arriver does the O-projection
    __threadfence();                 // release (drain stores + L2 writeback)
    __syncthreads();
    if (tid == 0) {
        int old = atomicAdd(&ctrs[b * 32 + blockIdx.x], 1);
        lastflag = (old == 7);
    }
    __syncthreads();
    if (!lastflag) return;
    __threadfence();                 // acquire (invalidate caches before reads)

    // ---- G2 tail: out[64 x 512] = attnb[rb0..+64] @ Wo, K = 512 ----
    {
        u16 (*As2)[64 * 32] = (u16 (*)[64 * 32])lds;     // [2][2048] = 8 KB
        uint32_t* Bs2U = (uint32_t*)(lds + 8192);        // [256*20] u32 = 20 KB
        u16* Bs2 = (u16*)Bs2U;

        const int rb0 = b * QL + q0;
        const int am0 = tid >> 2;
        const int ak0 = (tid & 3) * 8;
        const u16* gA2 = attnb + (size_t)(rb0 + am0) * HDIM + ak0;
        const int kkp = tid & 15;
        const int c4n = (tid >> 4) * 4;                  // 0..60

        const int wm2 = (w & 1) * 32;
        const int wn2 = (w >> 1) * 128;
        const int fc = lane & 15;
        const int fr = (lane >> 4) * 4;

        for (int nh = 0; nh < 2; nh++) {
            const float* wb = Wo + (size_t)(2 * kkp) * DM + nh * 256 + c4n;
            float4 a0, b0, a1, b1, a2, b2, a3, b3;
#define B2LOAD(kt) do { \
    a0 = *(const float4*)(wb + (size_t)(kt) * DM);        b0 = *(const float4*)(wb + (size_t)(kt) * DM + DM); \
    a1 = *(const float4*)(wb + (size_t)(kt) * DM + 64);   b1 = *(const float4*)(wb + (size_t)(kt) * DM + DM + 64); \
    a2 = *(const float4*)(wb + (size_t)(kt) * DM + 128);  b2 = *(const float4*)(wb + (size_t)(kt) * DM + DM + 128); \
    a3 = *(const float4*)(wb + (size_t)(kt) * DM + 192);  b3 = *(const float4*)(wb + (size_t)(kt) * DM + DM + 192); \
} while (0)
#define B2WRITE() do { \
    Bs2U[(c4n + 0) * 20 + kkp]         = packbf(a0.x, b0.x); \
    Bs2U[(c4n + 1) * 20 + kkp]         = packbf(a0.y, b0.y); \
    Bs2U[(c4n + 2) * 20 + kkp]         = packbf(a0.z, b0.z); \
    Bs2U[(c4n + 3) * 20 + kkp]         = packbf(a0.w, b0.w); \
    Bs2U[(64 + c4n + 0) * 20 + kkp]    = packbf(a1.x, b1.x); \
    Bs2U[(64 + c4n + 1) * 20 + kkp]    = packbf(a1.y, b1.y); \
    Bs2U[(64 + c4n + 2) * 20 + kkp]    = packbf(a1.z, b1.z); \
    Bs2U[(64 + c4n + 3) * 20 + kkp]    = packbf(a1.w, b1.w); \
    Bs2U[(128 + c4n + 0) * 20 + kkp]   = packbf(a2.x, b2.x); \
    Bs2U[(128 + c4n + 1) * 20 + kkp]   = packbf(a2.y, b2.y); \
    Bs2U[(128 + c4n + 2) * 20 + kkp]   = packbf(a2.z, b2.z); \
    Bs2U[(128 + c4n + 3) * 20 + kkp]   = packbf(a2.w, b2.w); \
    Bs2U[(192 + c4n + 0) * 20 + kkp]   = packbf(a3.x, b3.x); \
    Bs2U[(192 + c4n + 1) * 20 + kkp]   = packbf(a3.y, b3.y); \
    Bs2U[(192 + c4n + 2) * 20 + kkp]   = packbf(a3.z, b3.z); \
    Bs2U[(192 + c4n + 3) * 20 + kkp]   = packbf(a3.w, b3.w); \
} while (0)

            f32x4 acc2[2][8];
#pragma unroll
            for (int i = 0; i < 2; i++)
#pragma unroll
                for (int j = 0; j < 8; j++)
                    acc2[i][j] = (f32x4){0.f, 0.f, 0.f, 0.f};

            B2LOAD(0);
            GLLDS(gA2, &As2[0][(size_t)w * 512]);
            B2WRITE();
            __syncthreads();

            int cur2 = 0;
            for (int kt = 0; kt < KD; kt += 32) {
                const bool more = (kt + 32 < KD);
                if (more) {
                    GLLDS(gA2 + kt + 32, &As2[cur2 ^ 1][(size_t)w * 512]);
                    B2LOAD(kt + 32);
                }
                bf16x8 af2[2];
#pragma unroll
                for (int i = 0; i < 2; i++)
                    af2[i] = *(const bf16x8*)&As2[cur2][(wm2 + i * 16 + fm) * 32 + fk];
#pragma unroll
                for (int j = 0; j < 8; j++) {
                    bf16x8 bf2 = *(const bf16x8*)&Bs2[(wn2 + j * 16 + fm) * 40 + fk];
#pragma unroll
                    for (int i = 0; i < 2; i++)
                        acc2[i][j] = __builtin_amdgcn_mfma_f32_16x16x32_bf16(af2[i], bf2, acc2[i][j], 0, 0, 0);
                }
                __syncthreads();          // all waves done reading Bs2 / As2[cur^1] landed
                if (more) B2WRITE();
                __syncthreads();          // Bs2 for next step ready
                cur2 ^= 1;
            }
#undef B2LOAD
#undef B2WRITE

#pragma unroll
            for (int i = 0; i < 2; i++)
#pragma unroll
                for (int rr = 0; rr < 4; rr++) {
                    int row = rb0 + wm2 + i * 16 + fr + rr;
#pragma unroll
                    for (int j = 0; j < 8; j++) {
                        int col = nh * 256 + wn2 + j * 16 + fc;
                        out[(size_t)row * DM + col] = acc2[i][j][rr];
                    }
                }
            __syncthreads();   // before next nh's prologue overwrites Bs2
        }
    }
}

// ---------------------------------------------------------------------------
extern "C" void kernel_launch(void* const* d_in, const int* in_sizes, int n_in,
                              void* d_out, int out_size, void* d_ws, size_t ws_size,
                              hipStream_t stream)
{
    const float* x   = (const float*)d_in[0];
    const float* r   = (const float*)d_in[1];
    const float* Wkv = (const float*)d_in[2];
    const float* Wq  = (const float*)d_in[3];
    const float* bq  = (const float*)d_in[4];
    const float* Wr  = (const float*)d_in[5];
    const float* Wo  = (const float*)d_in[6];
    float* out = (float*)d_out;

    char* p = (char*)d_ws;
    u16* kvb    = (u16*)p;  p += (size_t)4224 * 1024 * 2;
    u16* hqb    = (u16*)p;  p += (size_t)4096 * 512 * 2;
    u16* hrb    = (u16*)p;  p += (size_t)64 * 512 * 2;
    u16* attnb  = (u16*)p;  p += (size_t)4096 * 512 * 2;
    float* maskv = (float*)p; p += 128 * sizeof(float);
    int* ctrs   = (int*)p;

    // 1) G1 + G3 + mask + ctr-zero (B staged from fp32 weights; no prep pass)
    hipLaunchKernelGGL(gemm_fused, dim3(928), dim3(256), 0, stream,
                       x, Wkv, Wq, bq, r, Wr, kvb, hqb, hrb, maskv, ctrs);
    // 2) attention + last-arriver O-projection
    hipLaunchKernelGGL(attn_mfma, dim3(QL / 64, NH, BB), dim3(256), 0, stream,
                       kvb, hqb, hrb, maskv, attnb, Wo, out, ctrs);
}